// Round 5
// baseline (684.830 us; speedup 1.0000x reference)
//
#include <hip/hip_runtime.h>
#include <hip/hip_fp16.h>

// Problem constants (hardcoded per reference): B=256, S=512, D=80, H=128, T=3
#define BB 256
#define SS 512
#define DD 80
#define HH 128
#define GG 512   // 4*H

typedef _Float16 h2_t __attribute__((ext_vector_type(2)));
typedef _Float16 half8 __attribute__((ext_vector_type(8)));
typedef float f32x4 __attribute__((ext_vector_type(4)));

union U32H2 { unsigned int u; h2_t h; unsigned short us[2]; };

static __device__ __forceinline__ h2_t u2h(unsigned int u) { U32H2 x; x.u = u; return x.h; }

static __device__ __forceinline__ unsigned int pk2(float a, float b) {
  unsigned int lo = (unsigned int)__half_as_ushort(__float2half(a));
  unsigned int hi = (unsigned int)__half_as_ushort(__float2half(b));
  return (hi << 16) | lo;
}

static __device__ __forceinline__ float fdot2(unsigned int a, unsigned int b, float c) {
#if __has_builtin(__builtin_amdgcn_fdot2)
  return __builtin_amdgcn_fdot2(u2h(a), u2h(b), c, false);
#else
  U32H2 ua, ub; ua.u = a; ub.u = b;
  return c + (float)ua.h[0] * (float)ub.h[0] + (float)ua.h[1] * (float)ub.h[1];
#endif
}

static __device__ __forceinline__ float fsig(float x) {
  return __fdividef(1.f, 1.f + __expf(-x));
}

// ---------------------------------------------------------------------------
// Kernel 1: prep. Wc = W_ih @ W_in (fp16, [512][80]), Whh fp16 [512][128],
// bias_comb = W_ih@b_in + b_ih + b_hh (fp32 [512]).
// ---------------------------------------------------------------------------
__global__ __launch_bounds__(128) void prep_kernel(
    const float* __restrict__ W_in, const float* __restrict__ b_in,
    const float* __restrict__ W_ih, const float* __restrict__ b_ih,
    const float* __restrict__ W_hh, const float* __restrict__ b_hh,
    unsigned short* __restrict__ wc16, unsigned short* __restrict__ whh16,
    float* __restrict__ biasc)
{
  const int g = blockIdx.x;     // 0..511
  const int t = threadIdx.x;    // 0..127
  const float* wih = W_ih + g * 256;
  if (t < DD) {
    float s = 0.f;
    for (int e = 0; e < 256; ++e) s += wih[e] * W_in[e * DD + t];
    wc16[g * DD + t] = __half_as_ushort(__float2half(s));
  }
  whh16[g * HH + t] = __half_as_ushort(__float2half(W_hh[g * HH + t]));
  if (t == 0) {
    float s = 0.f;
    for (int e = 0; e < 256; ++e) s += wih[e] * b_in[e];
    biasc[g] = s + b_ih[g] + b_hh[g];
  }
}

// ---------------------------------------------------------------------------
// Kernel 2 (MFMA): gates_x = x @ Wc.T via v_mfma_f32_16x16x32_f16, K=80
// zero-padded to 96 in LDS. Output in the scan's PERMUTED layout:
// col(g) = ((g&127)<<2) | (g>>7)  — so the scan (gate q=t&3, hidx=t>>2)
// loads gx at column t, perfectly coalesced.
// R4 NaN fix: B pad loop covered only 768 of 128rows*12 = 1536 pad dwords;
// rows 64..127 kept stale LDS in k=80..95 and 0 (A-pad) * Inf/NaN (stale)
// = NaN in the MFMA accumulate. Now every LDS dword a fragment reads is
// written by this kernel.
// ---------------------------------------------------------------------------
__global__ __launch_bounds__(256) void gemm_kernel(
    const float* __restrict__ x,
    const unsigned int* __restrict__ wc,   // [512][40] dwords (fp16x2)
    uint4* __restrict__ gx)
{
  __shared__ unsigned int Al[64 * 52];
  __shared__ unsigned int Bl[128 * 52];
  const int t  = threadIdx.x;
  const int mt = blockIdx.x;             // 0..2047 (m-tile of 64 rows)
  const int g0 = blockIdx.y * 128;       // gate tile base

  // stage A: 64 rows x 80 fp32 -> fp16x2, pad dwords 40..51 with 0
  {
    const float4* xr = (const float4*)(x + (size_t)mt * 64 * DD);
    #pragma unroll
    for (int i = 0; i < 5; ++i) {
      int f = t + i * 256;               // < 1280
      int row = f / 20, c4 = f % 20;
      float4 v = xr[row * 20 + c4];
      Al[row * 52 + c4 * 2]     = pk2(v.x, v.y);
      Al[row * 52 + c4 * 2 + 1] = pk2(v.z, v.w);
    }
    #pragma unroll
    for (int i = 0; i < 3; ++i) {
      int f = t + i * 256;               // < 768 = 64 rows * 12
      int row = f / 12, c = f % 12;
      Al[row * 52 + 40 + c] = 0u;
    }
  }
  // stage B: Wc rows g0..g0+127 (40 dwords each), pad dwords 40..51 with 0
  {
    #pragma unroll
    for (int i = 0; i < 5; ++i) {
      int f = t + i * 256;               // < 1280 uint4
      int row = f / 10, c4 = f % 10;
      uint4 v = *(const uint4*)(wc + (size_t)(g0 + row) * 40 + c4 * 4);
      *(uint4*)&Bl[row * 52 + c4 * 4] = v;
    }
    #pragma unroll
    for (int i = 0; i < 6; ++i) {
      int f = t + i * 256;               // < 1536 = 128 rows * 12  (FIX)
      int row = f / 12, c = f % 12;
      Bl[row * 52 + 40 + c] = 0u;
    }
  }
  __syncthreads();

  const int w = t >> 6, lane = t & 63;
  const int m = lane & 15, q = lane >> 4;

  // A-frag: A[mrow = w*16+m][k = kk*32 + q*8 + j], 16B contiguous
  half8 af[3];
  #pragma unroll
  for (int kk = 0; kk < 3; ++kk)
    af[kk] = *(const half8*)((const char*)Al + (size_t)(w * 16 + m) * 208 + kk * 64 + q * 16);

  #pragma unroll
  for (int j = 0; j < 8; ++j) {
    f32x4 acc = {0.f, 0.f, 0.f, 0.f};
    #pragma unroll
    for (int kk = 0; kk < 3; ++kk) {
      // B-frag: B[k][n] with n = g0+j*16+m  <=>  Wc_lds[j*16+m][k]
      half8 bf = *(const half8*)((const char*)Bl + (size_t)(j * 16 + m) * 208 + kk * 64 + q * 16);
      acc = __builtin_amdgcn_mfma_f32_16x16x32_f16(af[kk], bf, acc, 0, 0, 0);
    }
    // D layout: row mrow = w*16 + q*4 + r, col = j*16 + m
    unsigned int lo  = pk2(acc[0], acc[1]);       // s offsets q*4+0, q*4+1
    unsigned int hi  = pk2(acc[2], acc[3]);       // s offsets q*4+2, q*4+3
    unsigned int plo = (unsigned int)__shfl_down((int)lo, 16);
    unsigned int phi = (unsigned int)__shfl_down((int)hi, 16);
    if ((q & 1) == 0) {
      const int gl  = g0 + j * 16 + m;
      const int col = ((gl & 127) << 2) | (gl >> 7);   // scan permutation
      uint4 o; o.x = lo; o.y = hi; o.z = plo; o.w = phi;
      gx[((size_t)mt * 8 + w * 2 + (q >> 1)) * 512 + (size_t)col] = o;
    }
  }
}

// ---------------------------------------------------------------------------
// Kernel 3: the scan (identical to R4 — this round isolates the gemm fix).
// One wg per batch chain, 512 threads (8 waves). Thread t: gate q = t&3
// (0=i,1=f,2=g,3=o), h-index hi2 = t>>2. One gate/thread -> 64 weight
// dwords/thread, under the ~132-VGPR practical allocator ceiling seen in
// R2/R3. (i,f,g,o) of one h-index are adjacent lanes: exchange via 3x
// __shfl_xor + cndmask permute, c/h computed redundantly x4. Single
// barrier/step via double-buffered hbuf. gx read at column t (pre-permuted
// by gemm) -> fully coalesced uint4 loads.
// ---------------------------------------------------------------------------
__global__ __attribute__((amdgpu_waves_per_eu(2, 2))) __launch_bounds__(512)
void scan_kernel(
    const uint4* __restrict__ gx,     // [(b*64+sb)*512 + t]
    const uint4* __restrict__ whh,    // [512][16] uint4 (fp16 rows, logical g)
    const float* __restrict__ biasc,  // [512] logical g
    const float* __restrict__ wtime,  // [3]
    __half* __restrict__ hout)        // [B][S][128] fp16
{
  __shared__ unsigned int hbuf[2][64];  // h as fp16x2, double-buffered
  const int b    = blockIdx.x;
  const int t    = threadIdx.x;         // 0..511
  const int lane = t & 63;
  const int q    = t & 3;               // gate
  const int hi2  = t >> 2;              // 0..127
  const int g    = q * 128 + hi2;       // logical gate row

  unsigned int w[64];
  {
    const uint4* wr = whh + (size_t)g * 16;
    #pragma unroll
    for (int i = 0; i < 16; ++i) {
      uint4 v = wr[i];
      w[4*i] = v.x; w[4*i+1] = v.y; w[4*i+2] = v.z; w[4*i+3] = v.w;
    }
  }
  const float bias = biasc[g];
  const float wt0 = wtime[0], wt1 = wtime[1], wt2 = wtime[2];
  if (t < 64) { hbuf[0][t] = 0u; hbuf[1][t] = 0u; }
  float c = 0.f, hst0 = 0.f, hst1 = 0.f, cst0 = 0.f, cst1 = 0.f;
  int slot = 0, s = 0;
  const uint4* gxp = gx + (size_t)b * 64 * 512 + t;
  __syncthreads();

  uint4 gv = gxp[0];
  for (int sb = 0; sb < 64; ++sb) {
    uint4 gn = gv;                       // init (R4 had UB at sb==63)
    if (sb < 63) gn = gxp[(size_t)(sb + 1) * 512];
    unsigned int ga[4] = {gv.x, gv.y, gv.z, gv.w};
    #pragma unroll
    for (int i = 0; i < 8; ++i) {
      const int par = s & 1;
      const unsigned int hreg = hbuf[par][lane];
      U32H2 gu; gu.u = ga[i >> 1];
      const float gxi = (float)gu.h[i & 1];
      // 128-long dot, 4 independent chains
      float d0 = bias + gxi, d1 = 0.f, d2 = 0.f, d3 = 0.f;
      #pragma unroll
      for (int p = 0; p < 64; p += 4) {
        int h0 = __builtin_amdgcn_readlane((int)hreg, p);
        int h1 = __builtin_amdgcn_readlane((int)hreg, p + 1);
        int h2 = __builtin_amdgcn_readlane((int)hreg, p + 2);
        int h3 = __builtin_amdgcn_readlane((int)hreg, p + 3);
        d0 = fdot2(w[p],     (unsigned int)h0, d0);
        d1 = fdot2(w[p + 1], (unsigned int)h1, d1);
        d2 = fdot2(w[p + 2], (unsigned int)h2, d2);
        d3 = fdot2(w[p + 3], (unsigned int)h3, d3);
      }
      const float d = (d0 + d1) + (d2 + d3);
      // own activation: tanh for gate 2 (via 2*sigmoid(2x)-1), sigmoid else
      const float din = (q == 2) ? d + d : d;
      const float sv  = fsig(din);
      const float a   = (q == 2) ? 2.f * sv - 1.f : sv;
      // quad exchange: v_m = activation of gate q^m
      const float v1 = __shfl_xor(a, 1);
      const float v2 = __shfl_xor(a, 2);
      const float v3 = __shfl_xor(a, 3);
      const int b0 = q & 1, b1 = q >> 1;
      const float iv = b1 ? (b0 ? v3 : v2) : (b0 ? v1 : a);   // gate 0
      const float fv = b1 ? (b0 ? v2 : v3) : (b0 ? a  : v1);  // gate 1
      const float gg = b1 ? (b0 ? v1 : a ) : (b0 ? v3 : v2);  // gate 2
      const float ov = b1 ? (b0 ? a  : v1) : (b0 ? v2 : v3);  // gate 3
      c = fv * c + iv * gg;
      const float tc = 2.f * fsig(c + c) - 1.f;   // tanh(c)
      const float hn = ov * tc;
      float hcur;
      if (slot == 2) {
        hcur = hst0 * wt0 + hst1 * wt1 + hn * wt2;
        c    = cst0 * wt0 + cst1 * wt1 + c  * wt2;
        slot = 0;
      } else {
        hcur = hn;
        if (slot == 0) { hst0 = hn; cst0 = c; }
        else           { hst1 = hn; cst1 = c; }
        ++slot;
      }
      if (q == 0) {
        const __half hh2 = __float2half(hcur);
        ((__half*)hbuf[par ^ 1])[hi2] = hh2;
        hout[((size_t)b * SS + s) * HH + hi2] = hh2;
      }
      ++s;
      __syncthreads();
    }
    gv = gn;
  }
}

// ---------------------------------------------------------------------------
// Kernel 4: epilogue. logits = h @ W_br.T + b_br, then log_softmax over 4.
// One thread per (b,s) row.
// ---------------------------------------------------------------------------
__global__ __launch_bounds__(256) void out_kernel(
    const uint4* __restrict__ hout,   // [B*S][16] uint4 (fp16 rows)
    const float* __restrict__ Wbr, const float* __restrict__ bbr,
    float4* __restrict__ out)
{
  __shared__ unsigned int wb[4][64];
  __shared__ float bbs[4];
  const int t = threadIdx.x;
  {
    const int o = t >> 6, p = t & 63;
    wb[o][p] = pk2(Wbr[o * HH + 2 * p], Wbr[o * HH + 2 * p + 1]);
  }
  if (t < 4) bbs[t] = bbr[t];
  __syncthreads();

  const size_t row = (size_t)blockIdx.x * 256 + t;
  const uint4* hr = hout + row * 16;
  float a0 = bbs[0], a1 = bbs[1], a2 = bbs[2], a3 = bbs[3];
  #pragma unroll
  for (int qq = 0; qq < 16; ++qq) {
    uint4 hv = hr[qq];
    unsigned int hd[4] = {hv.x, hv.y, hv.z, hv.w};
    #pragma unroll
    for (int d = 0; d < 4; ++d) {
      const int p = qq * 4 + d;
      a0 = fdot2(hd[d], wb[0][p], a0);
      a1 = fdot2(hd[d], wb[1][p], a1);
      a2 = fdot2(hd[d], wb[2][p], a2);
      a3 = fdot2(hd[d], wb[3][p], a3);
    }
  }
  const float m = fmaxf(fmaxf(a0, a1), fmaxf(a2, a3));
  const float e0 = __expf(a0 - m), e1 = __expf(a1 - m), e2 = __expf(a2 - m), e3 = __expf(a3 - m);
  const float lse = m + __logf(e0 + e1 + e2 + e3);
  out[row] = make_float4(a0 - lse, a1 - lse, a2 - lse, a3 - lse);
}

// ---------------------------------------------------------------------------
extern "C" void kernel_launch(void* const* d_in, const int* in_sizes, int n_in,
                              void* d_out, int out_size, void* d_ws, size_t ws_size,
                              hipStream_t stream) {
  const float* x     = (const float*)d_in[0];
  const float* W_in  = (const float*)d_in[1];
  const float* b_in  = (const float*)d_in[2];
  const float* W_ih  = (const float*)d_in[3];
  const float* b_ih  = (const float*)d_in[4];
  const float* W_hh  = (const float*)d_in[5];
  const float* b_hh  = (const float*)d_in[6];
  const float* wtime = (const float*)d_in[7];
  const float* W_br  = (const float*)d_in[8];
  const float* b_br  = (const float*)d_in[9];
  (void)in_sizes; (void)n_in; (void)out_size; (void)ws_size;

  char* ws = (char*)d_ws;
  // ws layout (bytes, all 256-aligned):
  //   wc16  @ 0         : 512*80*2   = 81920
  //   whh16 @ 81920     : 512*128*2  = 131072
  //   biasc @ 212992    : 512*4      = 2048
  //   hout  @ 215040    : 256*512*128*2 = 33554432
  //   gx    @ 33769472  : 256*64*512*16 = 134217728   (end = 167987200)
  unsigned short* wc16  = (unsigned short*)(ws + 0);
  unsigned short* whh16 = (unsigned short*)(ws + 81920);
  float*          biasc = (float*)(ws + 212992);
  __half*         hout  = (__half*)(ws + 215040);
  uint4*          gx    = (uint4*)(ws + 33769472);

  prep_kernel<<<512, 128, 0, stream>>>(W_in, b_in, W_ih, b_ih, W_hh, b_hh,
                                       wc16, whh16, biasc);
  gemm_kernel<<<dim3(2048, 4), 256, 0, stream>>>(x, (const unsigned int*)wc16, gx);
  scan_kernel<<<256, 512, 0, stream>>>(gx, (const uint4*)whh16, biasc, wtime, hout);
  out_kernel<<<512, 256, 0, stream>>>((const uint4*)hout, W_br, b_br, (float4*)d_out);
}

// Round 6
// 635.378 us; speedup vs baseline: 1.0778x; 1.0778x over previous
//
#include <hip/hip_runtime.h>
#include <hip/hip_fp16.h>

// Problem constants (hardcoded per reference): B=256, S=512, D=80, H=128, T=3
#define BB 256
#define SS 512
#define DD 80
#define HH 128
#define GG 512   // 4*H

typedef _Float16 h2_t __attribute__((ext_vector_type(2)));
typedef _Float16 half8 __attribute__((ext_vector_type(8)));
typedef float f32x4 __attribute__((ext_vector_type(4)));

union U32H2 { unsigned int u; h2_t h; unsigned short us[2]; };
union U4H8 { uint4 u; half8 h; };

static __device__ __forceinline__ h2_t u2h(unsigned int u) { U32H2 x; x.u = u; return x.h; }

static __device__ __forceinline__ unsigned int pk2(float a, float b) {
  unsigned int lo = (unsigned int)__half_as_ushort(__float2half(a));
  unsigned int hi = (unsigned int)__half_as_ushort(__float2half(b));
  return (hi << 16) | lo;
}

static __device__ __forceinline__ float fdot2(unsigned int a, unsigned int b, float c) {
#if __has_builtin(__builtin_amdgcn_fdot2)
  return __builtin_amdgcn_fdot2(u2h(a), u2h(b), c, false);
#else
  U32H2 ua, ub; ua.u = a; ub.u = b;
  return c + (float)ua.h[0] * (float)ub.h[0] + (float)ua.h[1] * (float)ub.h[1];
#endif
}

static __device__ __forceinline__ float fsig(float x) {
  return __fdividef(1.f, 1.f + __expf(-x));
}

// ---------------------------------------------------------------------------
// Kernel 1: prep. Wc = W_ih @ W_in (fp16, [512][80]), Whh fp16 [512][128],
// bias_comb = W_ih@b_in + b_ih + b_hh (fp32 [512]).
// ---------------------------------------------------------------------------
__global__ __launch_bounds__(128) void prep_kernel(
    const float* __restrict__ W_in, const float* __restrict__ b_in,
    const float* __restrict__ W_ih, const float* __restrict__ b_ih,
    const float* __restrict__ W_hh, const float* __restrict__ b_hh,
    unsigned short* __restrict__ wc16, unsigned short* __restrict__ whh16,
    float* __restrict__ biasc)
{
  const int g = blockIdx.x;     // 0..511
  const int t = threadIdx.x;    // 0..127
  const float* wih = W_ih + g * 256;
  if (t < DD) {
    float s = 0.f;
    for (int e = 0; e < 256; ++e) s += wih[e] * W_in[e * DD + t];
    wc16[g * DD + t] = __half_as_ushort(__float2half(s));
  }
  whh16[g * HH + t] = __half_as_ushort(__float2half(W_hh[g * HH + t]));
  if (t == 0) {
    float s = 0.f;
    for (int e = 0; e < 256; ++e) s += wih[e] * b_in[e];
    biasc[g] = s + b_ih[g] + b_hh[g];
  }
}

// ---------------------------------------------------------------------------
// Kernel 2 (MFMA): gates_x = x @ Wc.T via v_mfma_f32_16x16x32_f16, K=80
// zero-padded to 96 in LDS. Output in the scan's PERMUTED layout:
// col(g) = ((g&127)<<2) | (g>>7)  — so the scan (gate q=t&3, hidx=t>>2)
// loads gx at column t, perfectly coalesced. (R4 NaN fix retained: B pad
// loop covers all 128 rows * 12 pad dwords.)
// ---------------------------------------------------------------------------
__global__ __launch_bounds__(256) void gemm_kernel(
    const float* __restrict__ x,
    const unsigned int* __restrict__ wc,   // [512][40] dwords (fp16x2)
    uint4* __restrict__ gx)
{
  __shared__ unsigned int Al[64 * 52];
  __shared__ unsigned int Bl[128 * 52];
  const int t  = threadIdx.x;
  const int mt = blockIdx.x;             // 0..2047 (m-tile of 64 rows)
  const int g0 = blockIdx.y * 128;       // gate tile base

  {
    const float4* xr = (const float4*)(x + (size_t)mt * 64 * DD);
    #pragma unroll
    for (int i = 0; i < 5; ++i) {
      int f = t + i * 256;               // < 1280
      int row = f / 20, c4 = f % 20;
      float4 v = xr[row * 20 + c4];
      Al[row * 52 + c4 * 2]     = pk2(v.x, v.y);
      Al[row * 52 + c4 * 2 + 1] = pk2(v.z, v.w);
    }
    #pragma unroll
    for (int i = 0; i < 3; ++i) {
      int f = t + i * 256;               // < 768 = 64 rows * 12
      int row = f / 12, c = f % 12;
      Al[row * 52 + 40 + c] = 0u;
    }
  }
  {
    #pragma unroll
    for (int i = 0; i < 5; ++i) {
      int f = t + i * 256;               // < 1280 uint4
      int row = f / 10, c4 = f % 10;
      uint4 v = *(const uint4*)(wc + (size_t)(g0 + row) * 40 + c4 * 4);
      *(uint4*)&Bl[row * 52 + c4 * 4] = v;
    }
    #pragma unroll
    for (int i = 0; i < 6; ++i) {
      int f = t + i * 256;               // < 1536 = 128 rows * 12
      int row = f / 12, c = f % 12;
      Bl[row * 52 + 40 + c] = 0u;
    }
  }
  __syncthreads();

  const int w = t >> 6, lane = t & 63;
  const int m = lane & 15, q = lane >> 4;

  half8 af[3];
  #pragma unroll
  for (int kk = 0; kk < 3; ++kk)
    af[kk] = *(const half8*)((const char*)Al + (size_t)(w * 16 + m) * 208 + kk * 64 + q * 16);

  #pragma unroll
  for (int j = 0; j < 8; ++j) {
    f32x4 acc = {0.f, 0.f, 0.f, 0.f};
    #pragma unroll
    for (int kk = 0; kk < 3; ++kk) {
      half8 bf = *(const half8*)((const char*)Bl + (size_t)(j * 16 + m) * 208 + kk * 64 + q * 16);
      acc = __builtin_amdgcn_mfma_f32_16x16x32_f16(af[kk], bf, acc, 0, 0, 0);
    }
    unsigned int lo  = pk2(acc[0], acc[1]);
    unsigned int hi  = pk2(acc[2], acc[3]);
    unsigned int plo = (unsigned int)__shfl_down((int)lo, 16);
    unsigned int phi = (unsigned int)__shfl_down((int)hi, 16);
    if ((q & 1) == 0) {
      const int gl  = g0 + j * 16 + m;
      const int col = ((gl & 127) << 2) | (gl >> 7);   // scan permutation
      uint4 o; o.x = lo; o.y = hi; o.z = plo; o.w = phi;
      gx[((size_t)mt * 8 + w * 2 + (q >> 1)) * 512 + (size_t)col] = o;
    }
  }
}

// ---------------------------------------------------------------------------
// Kernel 3: the scan, v4 — MFMA recurrence. One wg per batch chain
// (256 wgs, 512 thr = 8 waves, 2 waves/SIMD).
//
// R1-R5 lesson: the VALU dot (readlane + fdot2) never beat ~420us — either
// fdot2 lowers to a multi-inst fallback on gfx950 or the issue count is
// simply too high. v_mfma_f32_16x16x32_f16 is verified working on this
// chip (gemm passes), so move the per-step matvec to the matrix pipe:
//
// Phase A: wave wv owns gates 64wv..64wv+63 (4 tiles x 16). A-frag = W_hh
// in MFMA A layout, 64 VGPRs/lane, loaded ONCE and pinned with empty
// asm("+v") so the scheduler cannot sink/remat the loads into the loop
// (the R1/R2/R5 reload failure). B-frag = h broadcast across all 16 cols
// (4x ds_read_b128, conflict-free). D cols identical; lanes (L&15)==0
// write the 512 pre-activations (W.h only) to gbuf via ds_write_b128.
// Matrix cost: 128 MFMA/CU/step (16x n-redundant) ~= 512 cy/step floor.
//
// Phase B: R5's verified path — thread t: gate q=t&3, hidx=t>>2,
// d = gbuf[g] + bias + gx; quad shfl_xor exchange; redundant c/h update;
// pool slots; q==0 writes fp16 h to double-buffered hbuf + hout.
// Two barriers/step (gbuf ready, hbuf ready).
// ---------------------------------------------------------------------------
__global__ __attribute__((amdgpu_waves_per_eu(2, 2))) __launch_bounds__(512)
void scan_kernel(
    const uint4* __restrict__ gx,     // [(b*64+sb)*512 + t]
    const uint4* __restrict__ whh,    // [512][16] uint4 (fp16 rows, logical g)
    const float* __restrict__ biasc,  // [512] logical g
    const float* __restrict__ wtime,  // [3]
    __half* __restrict__ hout)        // [B][S][128] fp16
{
  __shared__ unsigned int hbuf[2][64];  // h as fp16x2, double-buffered
  __shared__ float gbuf[512];           // W_hh . h, by logical gate
  const int b    = blockIdx.x;
  const int t    = threadIdx.x;         // 0..511
  const int L    = t & 63;              // lane
  const int wv   = t >> 6;              // wave 0..7
  const int q    = t & 3;               // gate (phase B)
  const int hi2  = t >> 2;              // 0..127 (phase B)
  const int g    = q * 128 + hi2;       // logical gate row (phase B)

  // ---- A-frag preload: W_hh rows 64wv..64wv+63 in MFMA A layout ----
  // lane L, tile tt, kstep kk: A[m=L&15][k=kk*32+(L>>4)*8+j] =
  //   whh_row(64wv+tt*16+(L&15)) dwords [kk*16+(L>>4)*4 .. +3]
  half8 af[16];
  {
    const int gr = wv * 64 + (L & 15);
    #pragma unroll
    for (int tt = 0; tt < 4; ++tt) {
      #pragma unroll
      for (int kk = 0; kk < 4; ++kk) {
        U4H8 u;
        u.u = whh[(size_t)(gr + tt * 16) * 16 + kk * 4 + (L >> 4)];
        af[tt * 4 + kk] = u.h;
      }
    }
  }
  // Pin: forbid remat/sink of the weight loads into the loop.
  #pragma unroll
  for (int i = 0; i < 16; ++i) asm volatile("" : "+v"(af[i]));

  const float bias = biasc[g];
  const float wt0 = wtime[0], wt1 = wtime[1], wt2 = wtime[2];
  if (t < 64) { hbuf[0][t] = 0u; hbuf[1][t] = 0u; }
  float c = 0.f, hst0 = 0.f, hst1 = 0.f, cst0 = 0.f, cst1 = 0.f;
  int slot = 0, s = 0;
  const uint4* gxp = gx + (size_t)b * 64 * 512 + t;
  __syncthreads();

  uint4 gv = gxp[0];
  for (int sb = 0; sb < 64; ++sb) {
    uint4 gn = gv;
    if (sb < 63) gn = gxp[(size_t)(sb + 1) * 512];
    unsigned int ga[4] = {gv.x, gv.y, gv.z, gv.w};
    #pragma unroll 1
    for (int i = 0; i < 8; ++i) {
      const int par = s & 1;
      // ---- Phase A: gates_pre = W_hh . h via MFMA ----
      // B-frag: h broadcast over all 16 cols: lane L needs h dwords
      // [kk*16 + (L>>4)*4 .. +3]  (16-lane groups share an address).
      half8 bf[4];
      #pragma unroll
      for (int kk = 0; kk < 4; ++kk)
        bf[kk] = *(const half8*)((const char*)hbuf[par] + kk * 64 + (L >> 4) * 16);
      #pragma unroll
      for (int tt = 0; tt < 4; ++tt) {
        f32x4 acc = {0.f, 0.f, 0.f, 0.f};
        #pragma unroll
        for (int kk = 0; kk < 4; ++kk)
          acc = __builtin_amdgcn_mfma_f32_16x16x32_f16(af[tt * 4 + kk], bf[kk], acc, 0, 0, 0);
        // D: lane L holds rows (L>>4)*4+r (col L&15, all cols equal)
        if ((L & 15) == 0)
          *(f32x4*)&gbuf[wv * 64 + tt * 16 + (L >> 4) * 4] = acc;
      }
      __syncthreads();

      // ---- Phase B: activations + state update (R5-verified) ----
      U32H2 gu; gu.u = ga[i >> 1];
      const float gxi = (float)gu.h[i & 1];
      const float d = gbuf[g] + bias + gxi;
      const float din = (q == 2) ? d + d : d;
      const float sv  = fsig(din);
      const float a   = (q == 2) ? 2.f * sv - 1.f : sv;
      const float v1 = __shfl_xor(a, 1);
      const float v2 = __shfl_xor(a, 2);
      const float v3 = __shfl_xor(a, 3);
      const int b0 = q & 1, b1 = q >> 1;
      const float iv = b1 ? (b0 ? v3 : v2) : (b0 ? v1 : a);   // gate 0
      const float fv = b1 ? (b0 ? v2 : v3) : (b0 ? a  : v1);  // gate 1
      const float gg = b1 ? (b0 ? v1 : a ) : (b0 ? v3 : v2);  // gate 2
      const float ov = b1 ? (b0 ? a  : v1) : (b0 ? v2 : v3);  // gate 3
      c = fv * c + iv * gg;
      const float tc = 2.f * fsig(c + c) - 1.f;   // tanh(c)
      const float hn = ov * tc;
      float hcur;
      if (slot == 2) {
        hcur = hst0 * wt0 + hst1 * wt1 + hn * wt2;
        c    = cst0 * wt0 + cst1 * wt1 + c  * wt2;
        slot = 0;
      } else {
        hcur = hn;
        if (slot == 0) { hst0 = hn; cst0 = c; }
        else           { hst1 = hn; cst1 = c; }
        ++slot;
      }
      if (q == 0) {
        const __half hh2 = __float2half(hcur);
        ((__half*)hbuf[par ^ 1])[hi2] = hh2;
        hout[((size_t)b * SS + s) * HH + hi2] = hh2;
      }
      ++s;
      __syncthreads();
    }
    gv = gn;
  }
}

// ---------------------------------------------------------------------------
// Kernel 4: epilogue. logits = h @ W_br.T + b_br, then log_softmax over 4.
// One thread per (b,s) row.
// ---------------------------------------------------------------------------
__global__ __launch_bounds__(256) void out_kernel(
    const uint4* __restrict__ hout,   // [B*S][16] uint4 (fp16 rows)
    const float* __restrict__ Wbr, const float* __restrict__ bbr,
    float4* __restrict__ out)
{
  __shared__ unsigned int wb[4][64];
  __shared__ float bbs[4];
  const int t = threadIdx.x;
  {
    const int o = t >> 6, p = t & 63;
    wb[o][p] = pk2(Wbr[o * HH + 2 * p], Wbr[o * HH + 2 * p + 1]);
  }
  if (t < 4) bbs[t] = bbr[t];
  __syncthreads();

  const size_t row = (size_t)blockIdx.x * 256 + t;
  const uint4* hr = hout + row * 16;
  float a0 = bbs[0], a1 = bbs[1], a2 = bbs[2], a3 = bbs[3];
  #pragma unroll
  for (int qq = 0; qq < 16; ++qq) {
    uint4 hv = hr[qq];
    unsigned int hd[4] = {hv.x, hv.y, hv.z, hv.w};
    #pragma unroll
    for (int d = 0; d < 4; ++d) {
      const int p = qq * 4 + d;
      a0 = fdot2(hd[d], wb[0][p], a0);
      a1 = fdot2(hd[d], wb[1][p], a1);
      a2 = fdot2(hd[d], wb[2][p], a2);
      a3 = fdot2(hd[d], wb[3][p], a3);
    }
  }
  const float m = fmaxf(fmaxf(a0, a1), fmaxf(a2, a3));
  const float e0 = __expf(a0 - m), e1 = __expf(a1 - m), e2 = __expf(a2 - m), e3 = __expf(a3 - m);
  const float lse = m + __logf(e0 + e1 + e2 + e3);
  out[row] = make_float4(a0 - lse, a1 - lse, a2 - lse, a3 - lse);
}

// ---------------------------------------------------------------------------
extern "C" void kernel_launch(void* const* d_in, const int* in_sizes, int n_in,
                              void* d_out, int out_size, void* d_ws, size_t ws_size,
                              hipStream_t stream) {
  const float* x     = (const float*)d_in[0];
  const float* W_in  = (const float*)d_in[1];
  const float* b_in  = (const float*)d_in[2];
  const float* W_ih  = (const float*)d_in[3];
  const float* b_ih  = (const float*)d_in[4];
  const float* W_hh  = (const float*)d_in[5];
  const float* b_hh  = (const float*)d_in[6];
  const float* wtime = (const float*)d_in[7];
  const float* W_br  = (const float*)d_in[8];
  const float* b_br  = (const float*)d_in[9];
  (void)in_sizes; (void)n_in; (void)out_size; (void)ws_size;

  char* ws = (char*)d_ws;
  // ws layout (bytes, all 256-aligned):
  //   wc16  @ 0         : 512*80*2   = 81920
  //   whh16 @ 81920     : 512*128*2  = 131072
  //   biasc @ 212992    : 512*4      = 2048
  //   hout  @ 215040    : 256*512*128*2 = 33554432
  //   gx    @ 33769472  : 256*64*512*16 = 134217728   (end = 167987200)
  unsigned short* wc16  = (unsigned short*)(ws + 0);
  unsigned short* whh16 = (unsigned short*)(ws + 81920);
  float*          biasc = (float*)(ws + 212992);
  __half*         hout  = (__half*)(ws + 215040);
  uint4*          gx    = (uint4*)(ws + 33769472);

  prep_kernel<<<512, 128, 0, stream>>>(W_in, b_in, W_ih, b_ih, W_hh, b_hh,
                                       wc16, whh16, biasc);
  gemm_kernel<<<dim3(2048, 4), 256, 0, stream>>>(x, (const unsigned int*)wc16, gx);
  scan_kernel<<<256, 512, 0, stream>>>(gx, (const uint4*)whh16, biasc, wtime, hout);
  out_kernel<<<512, 256, 0, stream>>>((const uint4*)hout, W_br, b_br, (float4*)d_out);
}